// Round 1
// baseline (564.809 us; speedup 1.0000x reference)
//
#include <hip/hip_runtime.h>
#include <hip/hip_bf16.h>
#include <math.h>

// Problem constants (from setup_inputs): B=512, S=512, C=96.
#define BATCH 512
#define SEQ   512
#define NC    96
#define NTHR  128   // 2 waves; threads 0..95 own one state column each

#define NEG_INF (-1e30f)

__device__ __forceinline__ float wave_max_f(float v) {
    #pragma unroll
    for (int off = 32; off > 0; off >>= 1)
        v = fmaxf(v, __shfl_xor(v, off, 64));
    return v;
}
__device__ __forceinline__ float wave_sum_f(float v) {
    #pragma unroll
    for (int off = 32; off > 0; off >>= 1)
        v += __shfl_xor(v, off, 64);
    return v;
}
__device__ __forceinline__ int wave_sum_i(int v) {
    #pragma unroll
    for (int off = 32; off > 0; off >>= 1)
        v += __shfl_xor(v, off, 64);
    return v;
}

__global__ __launch_bounds__(NTHR, 1)
void crf_llh_kernel(const float* __restrict__ em,      // (B,S,C)
                    const int*   __restrict__ tags,    // (B,S)
                    const int*   __restrict__ masks,   // (B,S)
                    const float* __restrict__ startT,  // (C)
                    const float* __restrict__ endT,    // (C)
                    const float* __restrict__ trans,   // (C,C)
                    float*       __restrict__ out)     // scalar
{
    const int b    = blockIdx.x;
    const int j    = threadIdx.x;
    const int lane = j & 63;
    const int wid  = j >> 6;
    const bool active = (j < NC);
    const int jj = active ? j : 0;

    __shared__ __align__(16) float p_sh[2][NC];
    __shared__ float wmax_sh[2][2];
    __shared__ float redf_sh[2];
    __shared__ int   redi_sh[2];

    const float* em_b    = em    + (size_t)b * SEQ * NC;
    const int*   tags_b  = tags  + b * SEQ;
    const int*   masks_b = masks + b * SEQ;

    // ---- E column (exp of transitions) into registers: ecol[i] = exp(T[i][j])
    float ecol[NC];
    #pragma unroll
    for (int i = 0; i < NC; ++i)
        ecol[i] = __expf(trans[i * NC + jj]);

    // ---- alpha0 = start + em[0]
    float alpha = active ? (startT[jj] + em_b[jj]) : NEG_INF;

    // initial centering max (exact, via block reduce through wmax_sh[0])
    {
        float wm = wave_max_f(alpha);
        if (lane == 0) wmax_sh[0][wid] = wm;
    }
    __syncthreads();
    float m = fmaxf(wmax_sh[0][0], wmax_sh[0][1]);
    // first loop iteration uses buf=1, so wmax_sh[0] is not rewritten until
    // iteration s=2, whose writes come after the s=1 barrier -> safe.

    // ---- emissions/mask prefetch pipeline (distance 2)
    float em_cur = active ? em_b[1 * NC + jj] : 0.f;  // step s=1
    float em_nx1 = active ? em_b[2 * NC + jj] : 0.f;  // step s=2
    int   mk_cur = masks_b[1];
    int   mk_nx1 = masks_b[2];

    int buf = 1;
    for (int s = 1; s < SEQ; ++s) {
        const int sp = (s + 2 < SEQ) ? (s + 2) : (SEQ - 1);
        const float em_nx2 = active ? em_b[sp * NC + jj] : 0.f;
        const int   mk_nx2 = masks_b[sp];

        // p_j = exp(alpha - m)   (m is max of previous step's alpha: lag-1,
        // drift bounded by ~|em|+log C ~ 11, safe for fp32 exp)
        const float p_j = __expf(alpha - m);

        // wave max of current alpha -> centering value for NEXT step
        const float wm = wave_max_f(alpha);
        if (lane == 0) wmax_sh[buf][wid] = wm;
        if (active)    p_sh[buf][j] = p_j;
        __syncthreads();

        const float m_next = fmaxf(wmax_sh[buf][0], wmax_sh[buf][1]);

        // matvec: acc_j = sum_i p[i] * E[i][j], E column in registers,
        // p broadcast from LDS as float4
        const float4* p4 = reinterpret_cast<const float4*>(&p_sh[buf][0]);
        float a0 = 0.f, a1 = 0.f, a2 = 0.f, a3 = 0.f;
        #pragma unroll
        for (int i4 = 0; i4 < NC / 4; ++i4) {
            const float4 pv = p4[i4];
            a0 = fmaf(pv.x, ecol[4 * i4 + 0], a0);
            a1 = fmaf(pv.y, ecol[4 * i4 + 1], a1);
            a2 = fmaf(pv.z, ecol[4 * i4 + 2], a2);
            a3 = fmaf(pv.w, ecol[4 * i4 + 3], a3);
        }
        const float acc = (a0 + a1) + (a2 + a3);

        if (active && mk_cur)
            alpha = m + __logf(acc) + em_cur;
        m = m_next;

        em_cur = em_nx1; em_nx1 = em_nx2;
        mk_cur = mk_nx1; mk_nx1 = mk_nx2;
        buf ^= 1;
    }

    // ---- denominator = logsumexp_j(alpha_j + end_j)
    float v = active ? (alpha + endT[jj]) : NEG_INF;
    {
        float wm = wave_max_f(v);
        if (lane == 0) wmax_sh[0][wid] = wm;
    }
    __syncthreads();
    const float M = fmaxf(wmax_sh[0][0], wmax_sh[0][1]);
    float e = active ? __expf(v - M) : 0.f;
    {
        float ws = wave_sum_f(e);
        if (lane == 0) redf_sh[wid] = ws;
    }
    __syncthreads();
    const float denom = M + __logf(redf_sh[0] + redf_sh[1]);
    __syncthreads();  // protect redf_sh before numerator reuse

    // ---- numerator: gather scores along the tag path (all 128 threads)
    float nsum = 0.f;
    int   msum = 0;
    #pragma unroll
    for (int k = 0; k < SEQ / NTHR; ++k) {
        const int s  = j + NTHR * k;
        const int tg = tags_b[s];
        const int mk = masks_b[s];
        msum += (mk ? 1 : 0);
        if (s == 0) {
            nsum += startT[tg] + em_b[tg];
        } else if (mk) {
            const int tgp = tags_b[s - 1];
            nsum += trans[tgp * NC + tg] + em_b[s * NC + tg];
        }
    }
    nsum = wave_sum_f(nsum);
    msum = wave_sum_i(msum);
    if (lane == 0) { redf_sh[wid] = nsum; redi_sh[wid] = msum; }
    __syncthreads();
    if (j == 0) {
        float numer = redf_sh[0] + redf_sh[1];
        const int cnt = redi_sh[0] + redi_sh[1];   // number of valid steps
        const int last = tags_b[cnt - 1];
        numer += endT[last];
        atomicAdd(out, (numer - denom) * (1.0f / (float)BATCH));
    }
}

extern "C" void kernel_launch(void* const* d_in, const int* in_sizes, int n_in,
                              void* d_out, int out_size, void* d_ws, size_t ws_size,
                              hipStream_t stream) {
    const float* em     = (const float*)d_in[0];
    const int*   tags   = (const int*)  d_in[1];
    const int*   masks  = (const int*)  d_in[2];
    const float* startT = (const float*)d_in[3];
    const float* endT   = (const float*)d_in[4];
    const float* trans  = (const float*)d_in[5];
    float* out = (float*)d_out;

    hipMemsetAsync(out, 0, sizeof(float), stream);
    crf_llh_kernel<<<BATCH, NTHR, 0, stream>>>(em, tags, masks, startT, endT, trans, out);
}

// Round 3
// 420.648 us; speedup vs baseline: 1.3427x; 1.3427x over previous
//
#include <hip/hip_runtime.h>
#include <hip/hip_bf16.h>
#include <math.h>

// B=512, S=512, C=96. One 64-thread block (ONE wave) per batch chain.
// Lane l < 48 owns columns j0=2l, j1=2l+1. E=exp(T) columns live in
// registers as packed half2 (pairs along i). Per step: p=exp(alpha-m)*SC
// packed to fp16 in LDS (48 dwords), broadcast-read as 12 ds_read_b128,
// matvec via v_dot2_f32_f16 (fp32 accum). Lagged (1-step) centering max
// computed via DPP on the VALU pipe. No s_barrier (1-wave workgroup).

#define BATCH 512
#define SEQ   512
#define NC    96
#define NTHR  64
#define NEG_INF (-1e30f)
#define SC    0.25f                  // fp16 headroom scale
#define LSC   1.3862943611198906f    // -log(SC)

typedef __fp16 half2v __attribute__((ext_vector_type(2)));

// ---- DPP wave64 reduce (result broadcast via readlane 63) -------------
#define DPP_STEP_F(v, op, ctrl)                                              \
    v = op(v, __int_as_float(__builtin_amdgcn_update_dpp(                    \
            __float_as_int(v), __float_as_int(v), (ctrl), 0xf, 0xf, false)))

__device__ __forceinline__ float wave_max_all(float v) {
    DPP_STEP_F(v, fmaxf, 0x111);  // row_shr:1
    DPP_STEP_F(v, fmaxf, 0x112);  // row_shr:2
    DPP_STEP_F(v, fmaxf, 0x114);  // row_shr:4
    DPP_STEP_F(v, fmaxf, 0x118);  // row_shr:8
    DPP_STEP_F(v, fmaxf, 0x142);  // row_bcast:15
    DPP_STEP_F(v, fmaxf, 0x143);  // row_bcast:31
    return __int_as_float(__builtin_amdgcn_readlane(__float_as_int(v), 63));
}
__device__ __forceinline__ float fadd_(float a, float b) { return a + b; }
__device__ __forceinline__ float wave_sum_all(float v) {
    DPP_STEP_F(v, fadd_, 0x111);
    DPP_STEP_F(v, fadd_, 0x112);
    DPP_STEP_F(v, fadd_, 0x114);
    DPP_STEP_F(v, fadd_, 0x118);
    DPP_STEP_F(v, fadd_, 0x142);
    DPP_STEP_F(v, fadd_, 0x143);
    return __int_as_float(__builtin_amdgcn_readlane(__float_as_int(v), 63));
}

__global__ __launch_bounds__(NTHR, 1)
void crf_llh_kernel(const float* __restrict__ em,      // (B,S,C)
                    const int*   __restrict__ tags,    // (B,S)
                    const int*   __restrict__ masks,   // (B,S)
                    const float* __restrict__ startT,  // (C)
                    const float* __restrict__ endT,    // (C)
                    const float* __restrict__ trans,   // (C,C)
                    float*       __restrict__ out)     // scalar
{
    const int b = blockIdx.x;
    const int l = threadIdx.x;            // lane 0..63
    const bool active = (l < 48);
    const int j0 = active ? 2 * l     : 0;
    const int j1 = active ? 2 * l + 1 : 0;

    __shared__ __align__(16) half2v qsh[48];   // 192 B

    const float* em_b    = em    + (size_t)b * SEQ * NC;
    const int*   tags_b  = tags  + b * SEQ;
    const int*   masks_b = masks + b * SEQ;

    // ---- E columns (exp of transitions), packed half2 pairs along i ----
    half2v e0[48], e1[48];
    #pragma unroll
    for (int k = 0; k < 48; ++k) {
        const float t00 = trans[(2 * k)     * NC + j0];
        const float t01 = trans[(2 * k + 1) * NC + j0];
        const float t10 = trans[(2 * k)     * NC + j1];
        const float t11 = trans[(2 * k + 1) * NC + j1];
        e0[k] = __builtin_amdgcn_cvt_pkrtz(__expf(t00), __expf(t01));
        e1[k] = __builtin_amdgcn_cvt_pkrtz(__expf(t10), __expf(t11));
    }

    // ---- alpha0 = start + em[0]
    float a0 = active ? (startT[j0] + em_b[j0]) : NEG_INF;
    float a1 = active ? (startT[j1] + em_b[j1]) : NEG_INF;
    float m  = wave_max_all(fmaxf(a0, a1));    // exact initial max

    // ---- prefetch pipeline (distance 2) for emissions + mask
    const float2* em2 = reinterpret_cast<const float2*>(em_b);
    float2 emA = em2[1 * (NC / 2) + l % 48];   // step 1  (inactive lanes: harmless)
    float2 emB = em2[2 * (NC / 2) + l % 48];   // step 2
    int mkA = masks_b[1];
    int mkB = masks_b[2];

    for (int s = 1; s < SEQ; ++s) {
        const int sp = (s + 2 < SEQ) ? (s + 2) : (SEQ - 1);
        const float2 emN = em2[sp * (NC / 2) + l % 48];
        const int    mkN = masks_b[sp];

        // next-step centering max (lag-1) -- VALU/DPP pipe
        const float wm = wave_max_all(fmaxf(a0, a1));

        // p = exp(alpha - m) * SC, packed fp16 -> LDS
        const float p0 = __expf(a0 - m) * SC;
        const float p1 = __expf(a1 - m) * SC;
        const half2v ph = __builtin_amdgcn_cvt_pkrtz(p0, p1);
        if (active) qsh[l] = ph;
        __syncthreads();   // 1-wave workgroup: lowers to waitcnt only

        // matvec: acc_j = sum_i p_i * E[i][j] via v_dot2_f32_f16
        float acc0a = 0.f, acc0b = 0.f, acc1a = 0.f, acc1b = 0.f;
        const uint4* q4 = reinterpret_cast<const uint4*>(qsh);
        #pragma unroll
        for (int t = 0; t < 12; ++t) {
            const uint4 qv = q4[t];
            const half2v qx = __builtin_bit_cast(half2v, qv.x);
            const half2v qy = __builtin_bit_cast(half2v, qv.y);
            const half2v qz = __builtin_bit_cast(half2v, qv.z);
            const half2v qw = __builtin_bit_cast(half2v, qv.w);
            acc0a = __builtin_amdgcn_fdot2(qx, e0[4 * t + 0], acc0a, false);
            acc1a = __builtin_amdgcn_fdot2(qx, e1[4 * t + 0], acc1a, false);
            acc0a = __builtin_amdgcn_fdot2(qy, e0[4 * t + 1], acc0a, false);
            acc1a = __builtin_amdgcn_fdot2(qy, e1[4 * t + 1], acc1a, false);
            acc0b = __builtin_amdgcn_fdot2(qz, e0[4 * t + 2], acc0b, false);
            acc1b = __builtin_amdgcn_fdot2(qz, e1[4 * t + 2], acc1b, false);
            acc0b = __builtin_amdgcn_fdot2(qw, e0[4 * t + 3], acc0b, false);
            acc1b = __builtin_amdgcn_fdot2(qw, e1[4 * t + 3], acc1b, false);
        }
        const float acc0 = acc0a + acc0b;
        const float acc1 = acc1a + acc1b;

        const bool upd = active && (mkA != 0);
        const float na0 = m + __logf(acc0) + LSC + emA.x;
        const float na1 = m + __logf(acc1) + LSC + emA.y;
        a0 = upd ? na0 : a0;
        a1 = upd ? na1 : a1;
        m = wm;

        emA = emB; emB = emN;
        mkA = mkB; mkB = mkN;
    }

    // ---- denominator = logsumexp_j(alpha_j + end_j)
    const float v0 = active ? (a0 + endT[j0]) : NEG_INF;
    const float v1 = active ? (a1 + endT[j1]) : NEG_INF;
    const float M  = wave_max_all(fmaxf(v0, v1));
    const float e  = active ? (__expf(v0 - M) + __expf(v1 - M)) : 0.f;
    const float denom = M + __logf(wave_sum_all(e));

    // ---- numerator: gather along the tag path
    float nsum = 0.f;
    float msum = 0.f;
    #pragma unroll
    for (int k = 0; k < SEQ / NTHR; ++k) {
        const int s  = l + NTHR * k;
        const int tg = tags_b[s];
        const int mk = masks_b[s];
        msum += (mk ? 1.f : 0.f);
        if (s == 0) {
            nsum += startT[tg] + em_b[tg];
        } else if (mk) {
            nsum += trans[tags_b[s - 1] * NC + tg] + em_b[s * NC + tg];
        }
    }
    nsum = wave_sum_all(nsum);
    msum = wave_sum_all(msum);
    if (l == 0) {
        const int cnt  = (int)msum;
        const int last = tags_b[cnt - 1];
        atomicAdd(out, (nsum + endT[last] - denom) * (1.0f / (float)BATCH));
    }
}

extern "C" void kernel_launch(void* const* d_in, const int* in_sizes, int n_in,
                              void* d_out, int out_size, void* d_ws, size_t ws_size,
                              hipStream_t stream) {
    const float* em     = (const float*)d_in[0];
    const int*   tags   = (const int*)  d_in[1];
    const int*   masks  = (const int*)  d_in[2];
    const float* startT = (const float*)d_in[3];
    const float* endT   = (const float*)d_in[4];
    const float* trans  = (const float*)d_in[5];
    float* out = (float*)d_out;

    (void)hipMemsetAsync(out, 0, sizeof(float), stream);
    crf_llh_kernel<<<BATCH, NTHR, 0, stream>>>(em, tags, masks, startT, endT, trans, out);
}